// Round 2
// baseline (174.846 us; speedup 1.0000x reference)
//
#include <hip/hip_runtime.h>
#include <hip/hip_bf16.h>
#include <math.h>

#define H 128
#define R 8
#define TT 64
#define THREE_H 384
#define TWO_H 256

typedef short short8 __attribute__((ext_vector_type(8)));
typedef __bf16 bf16x8_t __attribute__((ext_vector_type(8)));
typedef float f32x4 __attribute__((ext_vector_type(4)));

__device__ inline void split_bf(float f, unsigned short& hi, unsigned short& lo) {
    unsigned u = __builtin_bit_cast(unsigned, f);
    hi = (unsigned short)(u >> 16);
    float fhi = __builtin_bit_cast(float, u & 0xffff0000u);
    float d = f - fhi;
    lo = (unsigned short)(__builtin_bit_cast(unsigned, d) >> 16);
}

__device__ inline f32x4 mfma_bf16(short8 a, short8 b, f32x4 c) {
    return __builtin_amdgcn_mfma_f32_16x16x32_bf16(
        __builtin_bit_cast(bf16x8_t, a), __builtin_bit_cast(bf16x8_t, b), c, 0, 0, 0);
}

// ---------------- zero scratch (floats + ints) ----------------
__global__ void k_zero2(float* p1, int n1, int* p2, int n2) {
    int i = blockIdx.x * 256 + threadIdx.x;
    if (i < n1) p1[i] = 0.f;
    if (i < n2) p2[i] = 0;
}

// ---------------- count edges per (rel, node, side) ----------------
__global__ void k_count(const int* __restrict__ src, const int* __restrict__ rel,
                        const int* __restrict__ dst, int* __restrict__ cs,
                        int* __restrict__ cd, int E, int Nn) {
    int e = blockIdx.x * 256 + threadIdx.x;
    if (e >= E) return;
    int r = rel[e];
    atomicAdd(&cs[r * Nn + src[e]], 1);
    atomicAdd(&cd[r * Nn + dst[e]], 1);
}

// ---------------- weighted accumulate: each node row read once ----------------
__global__ void k_accum(const float* __restrict__ nodes, const int* __restrict__ cs,
                        const int* __restrict__ cd, float* __restrict__ Sg,
                        float* __restrict__ cntg, int Nn, int nch) {
    int t = threadIdx.x;  // 256
    int n0 = blockIdx.x * nch, n1 = min(Nn, n0 + nch);
    int tS = ((t >> 7) << 8) + (t & 127);
    float sA[8] = {0, 0, 0, 0, 0, 0, 0, 0};
    float sB[8] = {0, 0, 0, 0, 0, 0, 0, 0};
    float ca[8] = {0, 0, 0, 0, 0, 0, 0, 0};
    for (int n = n0; n < n1; ++n) {
        float v = nodes[n * 256 + t];
#pragma unroll
        for (int r = 0; r < 8; ++r) {
            int a = cs[r * Nn + n];
            int b = cd[r * Nn + n];
            ca[r] += (float)a;
            sA[r] += (float)a * v;
            sB[r] += (float)b * v;
        }
    }
#pragma unroll
    for (int r = 0; r < 8; ++r) {
        atomicAdd(&Sg[r * 512 + tS], sA[r]);
        atomicAdd(&Sg[r * 512 + tS + 128], sB[r]);
    }
    if (t == 0) {
#pragma unroll
        for (int r = 0; r < 8; ++r) atomicAdd(&cntg[r], ca[r]);
    }
}

// ---------------- fallback: direct edge gather-sum ----------------
__global__ void k_edges(const float* __restrict__ nodes, const int* __restrict__ src,
                        const int* __restrict__ rel, const int* __restrict__ dst,
                        float* __restrict__ Sg, float* __restrict__ cntg, int E, int epb) {
    __shared__ float S[R * 512];
    __shared__ float cnt[R];
    int t = threadIdx.x;
    for (int i = t; i < R * 512; i += 256) S[i] = 0.f;
    if (t < R) cnt[t] = 0.f;
    __syncthreads();

    int e0 = blockIdx.x * epb;
    int e1 = min(E, e0 + epb);
    int tS = ((t >> 7) << 8) + (t & 127);

    if (e0 < e1) {
        int r = rel[e0];
        float vs = nodes[src[e0] * 256 + t];
        float vd = nodes[dst[e0] * 256 + t];
        for (int e = e0; e < e1; ++e) {
            int rn = 0; float vsn = 0.f, vdn = 0.f;
            if (e + 1 < e1) {
                rn = rel[e + 1];
                vsn = nodes[src[e + 1] * 256 + t];
                vdn = nodes[dst[e + 1] * 256 + t];
            }
            S[r * 512 + tS] += vs;
            S[r * 512 + tS + 128] += vd;
            if (t == 0) cnt[r] += 1.f;
            vs = vsn; vd = vdn; r = rn;
        }
    }
    __syncthreads();
    for (int i = t; i < R * 512; i += 256) atomicAdd(&Sg[i], S[i]);
    if (t < R) atomicAdd(&cntg[t], cnt[t]);
}

// ---------------- gx: [T][j][8] = x @ Wih^T + bih (+ bhh for r,z gates) ----------------
__global__ void k_gx(const float* __restrict__ x, const float* __restrict__ Wih,
                     const float* __restrict__ bih, const float* __restrict__ bhh,
                     float* __restrict__ gxT) {
    int tt = blockIdx.x >> 1, b = blockIdx.x & 1;
    __shared__ float xs[H];
    int t = threadIdx.x;  // 0..383
    if (t < H) xs[t] = x[(b * TT + tt) * H + t];
    __syncthreads();
    const float4* wp = (const float4*)(Wih + t * H);
    float acc = 0.f;
#pragma unroll
    for (int i = 0; i < 32; ++i) {
        float4 w = wp[i];
        acc += w.x * xs[4 * i] + w.y * xs[4 * i + 1] + w.z * xs[4 * i + 2] + w.w * xs[4 * i + 3];
    }
    float bias = bih[t] + (t < TWO_H ? bhh[t] : 0.f);  // bhh_n NOT folded (scaled by r)
    int k = t >> 7, j = t & 127;
    gxT[(tt * H + j) * 8 + b * 3 + k] = acc + bias;
}

// ---------------- combine: gs[b][h] = (sum_r S_r @ W_r + cnt_r*b_r)/E ----------------
__global__ void k_combine(const float* __restrict__ Sg, const float* __restrict__ cntg,
                          const float* __restrict__ relW, const float* __restrict__ relb,
                          float* __restrict__ gs, float invE) {
    int r = blockIdx.x;
    int t = threadIdx.x;  // 0..255
    __shared__ float Sl[512];
    Sl[t] = Sg[r * 512 + t];
    Sl[t + 256] = Sg[r * 512 + t + 256];
    __syncthreads();
    int b = t >> 7, h = t & 127;
    const float* W = relW + r * TWO_H * H;
    float acc = 0.f;
#pragma unroll 8
    for (int c = 0; c < TWO_H; ++c) acc += Sl[b * 256 + c] * W[c * H + h];
    acc += cntg[r] * relb[r * H + h];
    atomicAdd(&gs[t], acc * invE);
}

// ---------------- GRU (64 sequential steps) + MLP tail, single block ----------------
__launch_bounds__(512, 1)
__global__ void k_gru(const float* __restrict__ gxT, const float* __restrict__ Whh,
                      const float* __restrict__ bhh, const float* __restrict__ gs,
                      const float* __restrict__ W1, const float* __restrict__ b1,
                      const float* __restrict__ lng, const float* __restrict__ lnb,
                      const float* __restrict__ W2, const float* __restrict__ b2,
                      float* __restrict__ out) {
    // h double-buffered, hi/lo bf16 split; row 2 is an always-zero broadcast row.
    // Row pad to 144 ushorts (288B) -> rows land 8 banks apart: max 2-way aliasing (free).
    __shared__ __align__(16) unsigned short h_hi[2][3][144];
    __shared__ __align__(16) unsigned short h_lo[2][3][144];
    __shared__ float hf[256];
    __shared__ float gl[2][H];
    __shared__ float yl[2][TWO_H];
    __shared__ float red[16];

    int t = threadIdx.x;
    int w = t >> 6;
    int l = t & 63;

    for (int i = t; i < 2 * 3 * 144; i += 512) {
        ((unsigned short*)h_hi)[i] = 0;
        ((unsigned short*)h_lo)[i] = 0;
    }

    // B fragments: wave w owns n-tiles {w, w+8, w+16} = gates r,z,n for j in [16w,16w+16)
    short8 Bh[3][4], Bl[3][4];
#pragma unroll
    for (int k3 = 0; k3 < 3; ++k3) {
        int row = (w + 8 * k3) * 16 + (l & 15);
#pragma unroll
        for (int kt = 0; kt < 4; ++kt) {
            int kb = kt * 32 + (l >> 4) * 8;
            const float4* wp = (const float4*)(Whh + row * H + kb);
            float4 w0 = wp[0], w1 = wp[1];
            float ww[8] = {w0.x, w0.y, w0.z, w0.w, w1.x, w1.y, w1.z, w1.w};
            short8 hi8, lo8;
#pragma unroll
            for (int e = 0; e < 8; ++e) {
                unsigned short hh, ll2;
                split_bf(ww[e], hh, ll2);
                hi8[e] = (short)hh;
                lo8[e] = (short)ll2;
            }
            Bh[k3][kt] = hi8;
            Bl[k3][kt] = lo8;
        }
    }

    int ab = l & 15;
    int rr = ab < 2 ? ab : 2;  // rows >=2 broadcast the zero row
    int g = l >> 4;
    int j = w * 16 + ab;

    float hp0 = 0.f, hp1 = 0.f;
    float bhn = bhh[TWO_H + j];
    float4 cga = {0, 0, 0, 0}, cgb = {0, 0, 0, 0};
    if (l < 16) {
        const float4* gp = (const float4*)(gxT + j * 8);
        cga = gp[0];
        cgb = gp[1];
    }
    __syncthreads();

    for (int step = 0; step < TT; ++step) {
        int p = step & 1, q = p ^ 1;
        // prefetch next step's gx (drained by the end-of-step barrier, hidden by MFMA)
        float4 nga = {0, 0, 0, 0}, ngb = {0, 0, 0, 0};
        if (l < 16) {
            int sp = (step + 1) & 63;
            const float4* gp = (const float4*)(gxT + (sp * H + j) * 8);
            nga = gp[0];
            ngb = gp[1];
        }
        // A fragments (h hi/lo) from LDS buffer p
        short8 Ahi[4], Alo[4];
#pragma unroll
        for (int kt = 0; kt < 4; ++kt) {
            int kb = kt * 32 + g * 8;
            Ahi[kt] = *(const short8*)&h_hi[p][rr][kb];
            Alo[kt] = *(const short8*)&h_lo[p][rr][kb];
        }
        f32x4 aP[3], aQ[3], aS[3];
#pragma unroll
        for (int k3 = 0; k3 < 3; ++k3) {
            aP[k3] = (f32x4){0.f, 0.f, 0.f, 0.f};
            aQ[k3] = (f32x4){0.f, 0.f, 0.f, 0.f};
            aS[k3] = (f32x4){0.f, 0.f, 0.f, 0.f};
        }
#pragma unroll
        for (int kt = 0; kt < 4; ++kt) {
#pragma unroll
            for (int k3 = 0; k3 < 3; ++k3) {
                aP[k3] = mfma_bf16(Ahi[kt], Bh[k3][kt], aP[k3]);
                aQ[k3] = mfma_bf16(Alo[kt], Bh[k3][kt], aQ[k3]);
                aS[k3] = mfma_bf16(Ahi[kt], Bl[k3][kt], aS[k3]);
            }
        }
        if (l < 16) {
            float ghr0 = aP[0][0] + aQ[0][0] + aS[0][0];
            float ghr1 = aP[0][1] + aQ[0][1] + aS[0][1];
            float ghz0 = aP[1][0] + aQ[1][0] + aS[1][0];
            float ghz1 = aP[1][1] + aQ[1][1] + aS[1][1];
            float ghn0 = aP[2][0] + aQ[2][0] + aS[2][0];
            float ghn1 = aP[2][1] + aQ[2][1] + aS[2][1];

            float r0 = 1.f / (1.f + __expf(-(cga.x + ghr0)));
            float z0 = 1.f / (1.f + __expf(-(cga.y + ghz0)));
            float nn0 = cga.z + r0 * (ghn0 + bhn);
            float th0 = 2.f / (1.f + __expf(-2.f * nn0)) - 1.f;
            hp0 = (1.f - z0) * th0 + z0 * hp0;

            float r1 = 1.f / (1.f + __expf(-(cga.w + ghr1)));
            float z1 = 1.f / (1.f + __expf(-(cgb.x + ghz1)));
            float nn1 = cgb.y + r1 * (ghn1 + bhn);
            float th1 = 2.f / (1.f + __expf(-2.f * nn1)) - 1.f;
            hp1 = (1.f - z1) * th1 + z1 * hp1;

            unsigned short hh, ll2;
            split_bf(hp0, hh, ll2);
            h_hi[q][0][j] = hh;
            h_lo[q][0][j] = ll2;
            split_bf(hp1, hh, ll2);
            h_hi[q][1][j] = hh;
            h_lo[q][1][j] = ll2;

            cga = nga;
            cgb = ngb;
        }
        __syncthreads();
    }

    // ---- tail ----
    if (l < 16) {
        hf[j] = hp0;
        hf[128 + j] = hp1;
    }
    __syncthreads();
    if (t < 256) gl[t >> 7][t & 127] = gs[t] + hf[t];
    __syncthreads();

    float h1_0 = 0.f, h1_1 = 0.f;
    if (t < 256) {
        int o = t;
        h1_0 = b1[o];
        h1_1 = b1[o];
        for (int i = 0; i < H; ++i) {
            float wv = W1[i * TWO_H + o];
            h1_0 += gl[0][i] * wv;
            h1_1 += gl[1][i] * wv;
        }
    }
    float s10 = h1_0, s20 = h1_0 * h1_0, s11 = h1_1, s21 = h1_1 * h1_1;
    if (t >= 256) { s10 = s20 = s11 = s21 = 0.f; }
#pragma unroll
    for (int off = 32; off; off >>= 1) {
        s10 += __shfl_xor(s10, off);
        s20 += __shfl_xor(s20, off);
        s11 += __shfl_xor(s11, off);
        s21 += __shfl_xor(s21, off);
    }
    if (l == 0 && w < 4) {
        red[w * 4 + 0] = s10; red[w * 4 + 1] = s20;
        red[w * 4 + 2] = s11; red[w * 4 + 3] = s21;
    }
    __syncthreads();
    if (t < 256) {
        float S10 = red[0] + red[4] + red[8] + red[12];
        float S20 = red[1] + red[5] + red[9] + red[13];
        float S11 = red[2] + red[6] + red[10] + red[14];
        float S21 = red[3] + red[7] + red[11] + red[15];
        int o = t;
        float mu0 = S10 / 256.f, mu1 = S11 / 256.f;
        float v0 = S20 / 256.f - mu0 * mu0, v1 = S21 / 256.f - mu1 * mu1;
        float is0 = rsqrtf(v0 + 1e-5f), is1 = rsqrtf(v1 + 1e-5f);
        float y0 = (h1_0 - mu0) * is0 * lng[o] + lnb[o];
        float y1 = (h1_1 - mu1) * is1 * lng[o] + lnb[o];
        yl[0][o] = fmaxf(y0, 0.f);
        yl[1][o] = fmaxf(y1, 0.f);
    }
    __syncthreads();
    if (t < H) {
        int oo = t;
        float a0 = b2[oo], a1 = b2[oo];
        for (int i = 0; i < TWO_H; ++i) {
            float wv = W2[i * H + oo];
            a0 += yl[0][i] * wv;
            a1 += yl[1][i] * wv;
        }
        out[oo] = a0;
        out[H + oo] = a1;
    }
}

extern "C" void kernel_launch(void* const* d_in, const int* in_sizes, int n_in,
                              void* d_out, int out_size, void* d_ws, size_t ws_size,
                              hipStream_t stream) {
    const float* nodes = (const float*)d_in[0];
    const float* temporal = (const float*)d_in[1];
    const float* relW = (const float*)d_in[2];
    const float* relb = (const float*)d_in[3];
    const float* gru_Wih = (const float*)d_in[4];
    const float* gru_Whh = (const float*)d_in[5];
    const float* gru_bih = (const float*)d_in[6];
    const float* gru_bhh = (const float*)d_in[7];
    const float* mlp_W1 = (const float*)d_in[8];
    const float* mlp_b1 = (const float*)d_in[9];
    const float* ln_g = (const float*)d_in[10];
    const float* ln_b = (const float*)d_in[11];
    const float* mlp_W2 = (const float*)d_in[12];
    const float* mlp_b2 = (const float*)d_in[13];
    const int* src = (const int*)d_in[14];
    const int* rel = (const int*)d_in[15];
    const int* dst = (const int*)d_in[16];
    float* out = (float*)d_out;

    int E = in_sizes[14];
    int Nn = in_sizes[0] / 256;

    float* ws = (float*)d_ws;
    float* S = ws;              // 4096
    float* cnt = ws + 4096;     // 8
    float* gs = ws + 4104;      // 256
    float* gxT = ws + 4360;     // 65536
    int* cs = (int*)(ws + 69896);  // 8*Nn
    int* cd = cs + 8 * Nn;         // 8*Nn

    size_t need = (size_t)(69896 + 16 * Nn) * sizeof(float);
    if (ws_size >= need) {
        int nz = 16 * Nn;
        int zb = (max(4360, nz) + 255) / 256;
        k_zero2<<<zb, 256, 0, stream>>>(ws, 4360, cs, nz);
        k_count<<<(E + 255) / 256, 256, 0, stream>>>(src, rel, dst, cs, cd, E, Nn);
        k_accum<<<(Nn + 63) / 64, 256, 0, stream>>>(nodes, cs, cd, S, cnt, Nn, 64);
    } else {
        k_zero2<<<(4360 + 255) / 256, 256, 0, stream>>>(ws, 4360, (int*)ws, 0);
        int epb = (E + 1023) / 1024;
        k_edges<<<1024, 256, 0, stream>>>(nodes, src, rel, dst, S, cnt, E, epb);
    }

    k_gx<<<128, 384, 0, stream>>>(temporal, gru_Wih, gru_bih, gru_bhh, gxT);

    k_combine<<<8, 256, 0, stream>>>(S, cnt, relW, relb, gs, 1.f / (float)E);

    k_gru<<<1, 512, 0, stream>>>(gxT, gru_Whh, gru_bhh, gs, mlp_W1, mlp_b1,
                                 ln_g, ln_b, mlp_W2, mlp_b2, out);
}

// Round 3
// 129.562 us; speedup vs baseline: 1.3495x; 1.3495x over previous
//
#include <hip/hip_runtime.h>
#include <hip/hip_bf16.h>
#include <math.h>

#define H 128
#define TT 64
#define TWO_H 256

typedef short short8 __attribute__((ext_vector_type(8)));
typedef __bf16 bf16x8_t __attribute__((ext_vector_type(8)));
typedef float f32x4 __attribute__((ext_vector_type(4)));

__device__ inline void split_bf(float f, unsigned short& hi, unsigned short& lo) {
    unsigned u = __builtin_bit_cast(unsigned, f);
    hi = (unsigned short)(u >> 16);
    float fhi = __builtin_bit_cast(float, u & 0xffff0000u);
    float d = f - fhi;
    lo = (unsigned short)(__builtin_bit_cast(unsigned, d) >> 16);
}

__device__ inline f32x4 mfma_bf16(short8 a, short8 b, f32x4 c) {
    return __builtin_amdgcn_mfma_f32_16x16x32_bf16(
        __builtin_bit_cast(bf16x8_t, a), __builtin_bit_cast(bf16x8_t, b), c, 0, 0, 0);
}

// ================= K1: fused edge gather-sum + gx precompute =================
__global__ void k_front(const float* __restrict__ nodes, const int* __restrict__ src,
                        const int* __restrict__ rel, const int* __restrict__ dst,
                        const float* __restrict__ x, const float* __restrict__ Wih,
                        const float* __restrict__ bih, const float* __restrict__ bhh,
                        float* __restrict__ Sg, float* __restrict__ cntg,
                        float* __restrict__ gxT, int E, int NEB, int epb) {
    __shared__ float S[8 * 512];
    __shared__ float cnt[8];
    __shared__ float xs[H];
    int bid = blockIdx.x;
    int t = threadIdx.x;

    if (bid < NEB) {
        // ---- edge path: accumulate per-relation feature sums in LDS ----
        for (int i = t; i < 8 * 512; i += 256) S[i] = 0.f;
        if (t < 8) cnt[t] = 0.f;
        __syncthreads();

        int e0 = bid * epb, e1 = min(E, e0 + epb);
        int tS = ((t >> 7) << 8) + (t & 127);

        for (int e = e0; e < e1; e += 8) {
            float vsv[8], vdv[8];
            int rv[8];
#pragma unroll
            for (int i = 0; i < 8; ++i) {
                if (e + i < e1) {
                    rv[i] = rel[e + i];
                    vsv[i] = nodes[src[e + i] * 256 + t];
                    vdv[i] = nodes[dst[e + i] * 256 + t];
                } else {
                    rv[i] = 0; vsv[i] = 0.f; vdv[i] = 0.f;
                }
            }
            if (t == 0) {
#pragma unroll
                for (int i = 0; i < 8; ++i)
                    if (e + i < e1) cnt[rv[i]] += 1.f;
            }
#pragma unroll
            for (int i = 0; i < 8; ++i) {
                S[rv[i] * 512 + tS] += vsv[i];
                S[rv[i] * 512 + tS + 128] += vdv[i];
            }
        }
        __syncthreads();
        for (int i = t; i < 8 * 512; i += 256) atomicAdd(&Sg[i], S[i]);
        if (t < 8) atomicAdd(&cntg[t], cnt[t]);
    } else {
        // ---- gx path: gxT[tt][j][8] = x @ Wih^T + bih (+bhh folded for r,z) ----
        int b2 = bid - NEB;
        int tt = b2 >> 1, bb = b2 & 1;
        if (t < H) xs[t] = x[(bb * TT + tt) * H + t];
        __syncthreads();
        for (int o = t; o < 384; o += 256) {
            const float4* wp = (const float4*)(Wih + o * H);
            float acc = 0.f;
#pragma unroll
            for (int i = 0; i < 32; ++i) {
                float4 w = wp[i];
                acc += w.x * xs[4 * i] + w.y * xs[4 * i + 1] + w.z * xs[4 * i + 2] +
                       w.w * xs[4 * i + 3];
            }
            float bias = bih[o] + (o < TWO_H ? bhh[o] : 0.f);  // bhh_n not foldable
            int k = o >> 7, j = o & 127;
            gxT[(tt * H + j) * 8 + bb * 3 + k] = acc + bias;
        }
    }
}

// ================= K2: block0 = GRU+tail; blocks 1-8 = combine =================
__launch_bounds__(512, 1)
__global__ void k_back(const float* __restrict__ gxT, const float* __restrict__ Whh,
                       const float* __restrict__ bhh, const float* __restrict__ Sg,
                       const float* __restrict__ cntg, const float* __restrict__ relW,
                       const float* __restrict__ relb, float* __restrict__ gs,
                       int* __restrict__ flag, float invE,
                       const float* __restrict__ W1, const float* __restrict__ b1,
                       const float* __restrict__ lng, const float* __restrict__ lnb,
                       const float* __restrict__ W2, const float* __restrict__ b2v,
                       float* __restrict__ out) {
    int t = threadIdx.x;
    int w = t >> 6;
    int l = t & 63;

    if (blockIdx.x > 0) {
        // ---- combine: gs += (S_r @ W_r + cnt_r * b_r) / E ----
        int r = blockIdx.x - 1;
        if (t < 256) {
            int bb = t >> 7, h = t & 127;
            const float* Wr = relW + r * TWO_H * H;
            const float* Sr = Sg + r * 512 + bb * 256;
            float acc = 0.f;
#pragma unroll 8
            for (int c = 0; c < TWO_H; ++c) acc += Sr[c] * Wr[c * H + h];
            acc += cntg[r] * relb[r * H + h];
            atomicAdd(&gs[t], acc * invE);
        }
        __syncthreads();
        if (t == 0) {
            __threadfence();
            atomicAdd(flag, 1);
        }
        return;
    }

    // ---- block 0: GRU over 64 steps ----
    // h packed as A-rows: row0=b0_hi row1=b1_hi row2=b0_lo row3=b1_lo row4=zero
    __shared__ __align__(16) unsigned short h2[2][5][144];
    __shared__ float hf[256];
    __shared__ float gl[2][H];
    __shared__ float yl[2][TWO_H];
    __shared__ float red[16];

    for (int i = t; i < 2 * 5 * 144; i += 512) ((unsigned short*)h2)[i] = 0;

    // B fragments: wave w owns n-tiles {w, w+8, w+16} = gates r,z,n for j in [16w,16w+16)
    short8 Bh[3][4], Bl[3][4];
#pragma unroll
    for (int k3 = 0; k3 < 3; ++k3) {
        int row = (w + 8 * k3) * 16 + (l & 15);
#pragma unroll
        for (int kt = 0; kt < 4; ++kt) {
            int kb = kt * 32 + (l >> 4) * 8;
            const float4* wp = (const float4*)(Whh + row * H + kb);
            float4 w0 = wp[0], w1 = wp[1];
            float ww[8] = {w0.x, w0.y, w0.z, w0.w, w1.x, w1.y, w1.z, w1.w};
            short8 hi8, lo8;
#pragma unroll
            for (int e = 0; e < 8; ++e) {
                unsigned short hh, ll2;
                split_bf(ww[e], hh, ll2);
                hi8[e] = (short)hh;
                lo8[e] = (short)ll2;
            }
            Bh[k3][kt] = hi8;
            Bl[k3][kt] = lo8;
        }
    }

    int ab = l & 15;
    int g = l >> 4;
    int rr = ab < 4 ? ab : 4;  // lanes with A-row >=4 broadcast the zero row
    int j = w * 16 + ab;

    float hp0 = 0.f, hp1 = 0.f;
    float bhn = bhh[TWO_H + j];
    float4 cga = {0, 0, 0, 0}, cgb = {0, 0, 0, 0};
    if (l < 16) {
        const float4* gp = (const float4*)(gxT + j * 8);
        cga = gp[0];
        cgb = gp[1];
    }
    __syncthreads();

    for (int step = 0; step < TT; ++step) {
        int p = step & 1, q = p ^ 1;
        float4 nga = {0, 0, 0, 0}, ngb = {0, 0, 0, 0};
        if (l < 16) {
            int sp = (step + 1) & 63;
            const float4* gp = (const float4*)(gxT + (sp * H + j) * 8);
            nga = gp[0];
            ngb = gp[1];
        }
        short8 A[4];
#pragma unroll
        for (int kt = 0; kt < 4; ++kt)
            A[kt] = *(const short8*)&h2[p][rr][kt * 32 + g * 8];

        f32x4 c1[3], c2[3];
#pragma unroll
        for (int k3 = 0; k3 < 3; ++k3) {
            c1[k3] = (f32x4){0.f, 0.f, 0.f, 0.f};
            c2[k3] = (f32x4){0.f, 0.f, 0.f, 0.f};
        }
#pragma unroll
        for (int kt = 0; kt < 4; ++kt) {
#pragma unroll
            for (int k3 = 0; k3 < 3; ++k3) {
                c1[k3] = mfma_bf16(A[kt], Bh[k3][kt], c1[k3]);
                c2[k3] = mfma_bf16(A[kt], Bl[k3][kt], c2[k3]);
            }
        }
        if (l < 16) {
            // rows: 0=b0hi 1=b1hi 2=b0lo 3=b1lo; sum hi*hi + lo*hi + hi*lo + lo*lo
            float ghr0 = c1[0][0] + c1[0][2] + c2[0][0] + c2[0][2];
            float ghr1 = c1[0][1] + c1[0][3] + c2[0][1] + c2[0][3];
            float ghz0 = c1[1][0] + c1[1][2] + c2[1][0] + c2[1][2];
            float ghz1 = c1[1][1] + c1[1][3] + c2[1][1] + c2[1][3];
            float ghn0 = c1[2][0] + c1[2][2] + c2[2][0] + c2[2][2];
            float ghn1 = c1[2][1] + c1[2][3] + c2[2][1] + c2[2][3];

            float r0 = 1.f / (1.f + __expf(-(cga.x + ghr0)));
            float z0 = 1.f / (1.f + __expf(-(cga.y + ghz0)));
            float nn0 = cga.z + r0 * (ghn0 + bhn);
            float th0 = 2.f / (1.f + __expf(-2.f * nn0)) - 1.f;
            hp0 = (1.f - z0) * th0 + z0 * hp0;

            float r1 = 1.f / (1.f + __expf(-(cga.w + ghr1)));
            float z1 = 1.f / (1.f + __expf(-(cgb.x + ghz1)));
            float nn1 = cgb.y + r1 * (ghn1 + bhn);
            float th1 = 2.f / (1.f + __expf(-2.f * nn1)) - 1.f;
            hp1 = (1.f - z1) * th1 + z1 * hp1;

            unsigned short hh, ll2;
            split_bf(hp0, hh, ll2);
            h2[q][0][j] = hh;
            h2[q][2][j] = ll2;
            split_bf(hp1, hh, ll2);
            h2[q][1][j] = hh;
            h2[q][3][j] = ll2;

            cga = nga;
            cgb = ngb;
        }
        __syncthreads();
    }

    // ---- wait for combine blocks, then tail ----
    if (l < 16) {
        hf[j] = hp0;
        hf[128 + j] = hp1;
    }
    if (t == 0) {
        while (atomicAdd(flag, 0) < 8) {}
    }
    __syncthreads();
    if (t < 256) gl[t >> 7][t & 127] = atomicAdd(&gs[t], 0.f) + hf[t];
    __syncthreads();

    float h1_0 = 0.f, h1_1 = 0.f;
    if (t < 256) {
        int o = t;
        h1_0 = b1[o];
        h1_1 = b1[o];
        for (int i = 0; i < H; ++i) {
            float wv = W1[i * TWO_H + o];
            h1_0 += gl[0][i] * wv;
            h1_1 += gl[1][i] * wv;
        }
    }
    float s10 = h1_0, s20 = h1_0 * h1_0, s11 = h1_1, s21 = h1_1 * h1_1;
    if (t >= 256) { s10 = s20 = s11 = s21 = 0.f; }
#pragma unroll
    for (int off = 32; off; off >>= 1) {
        s10 += __shfl_xor(s10, off);
        s20 += __shfl_xor(s20, off);
        s11 += __shfl_xor(s11, off);
        s21 += __shfl_xor(s21, off);
    }
    if (l == 0 && w < 4) {
        red[w * 4 + 0] = s10; red[w * 4 + 1] = s20;
        red[w * 4 + 2] = s11; red[w * 4 + 3] = s21;
    }
    __syncthreads();
    if (t < 256) {
        float S10 = red[0] + red[4] + red[8] + red[12];
        float S20 = red[1] + red[5] + red[9] + red[13];
        float S11 = red[2] + red[6] + red[10] + red[14];
        float S21 = red[3] + red[7] + red[11] + red[15];
        int o = t;
        float mu0 = S10 / 256.f, mu1 = S11 / 256.f;
        float v0 = S20 / 256.f - mu0 * mu0, v1 = S21 / 256.f - mu1 * mu1;
        float is0 = rsqrtf(v0 + 1e-5f), is1 = rsqrtf(v1 + 1e-5f);
        float y0 = (h1_0 - mu0) * is0 * lng[o] + lnb[o];
        float y1 = (h1_1 - mu1) * is1 * lng[o] + lnb[o];
        yl[0][o] = fmaxf(y0, 0.f);
        yl[1][o] = fmaxf(y1, 0.f);
    }
    __syncthreads();
    if (t < H) {
        int oo = t;
        float a0 = b2v[oo], a1 = b2v[oo];
        for (int i = 0; i < TWO_H; ++i) {
            float wv = W2[i * H + oo];
            a0 += yl[0][i] * wv;
            a1 += yl[1][i] * wv;
        }
        out[oo] = a0;
        out[H + oo] = a1;
    }
}

extern "C" void kernel_launch(void* const* d_in, const int* in_sizes, int n_in,
                              void* d_out, int out_size, void* d_ws, size_t ws_size,
                              hipStream_t stream) {
    const float* nodes = (const float*)d_in[0];
    const float* temporal = (const float*)d_in[1];
    const float* relW = (const float*)d_in[2];
    const float* relb = (const float*)d_in[3];
    const float* gru_Wih = (const float*)d_in[4];
    const float* gru_Whh = (const float*)d_in[5];
    const float* gru_bih = (const float*)d_in[6];
    const float* gru_bhh = (const float*)d_in[7];
    const float* mlp_W1 = (const float*)d_in[8];
    const float* mlp_b1 = (const float*)d_in[9];
    const float* ln_g = (const float*)d_in[10];
    const float* ln_b = (const float*)d_in[11];
    const float* mlp_W2 = (const float*)d_in[12];
    const float* mlp_b2 = (const float*)d_in[13];
    const int* src = (const int*)d_in[14];
    const int* rel = (const int*)d_in[15];
    const int* dst = (const int*)d_in[16];
    float* out = (float*)d_out;

    int E = in_sizes[14];

    float* ws = (float*)d_ws;
    float* Sg = ws;                    // 4096
    float* cntg = ws + 4096;           // 8
    float* gs = ws + 4104;             // 256
    int* flag = (int*)(ws + 4360);     // 1
    float* gxT = ws + 4368;            // 65536

    // zero S/cnt/gs/flag in one async memset (graph-capturable)
    hipMemsetAsync(d_ws, 0, 4361 * sizeof(float), stream);

    const int NEB = 512;
    int epb = (E + NEB - 1) / NEB;
    k_front<<<NEB + 2 * TT, 256, 0, stream>>>(nodes, src, rel, dst, temporal, gru_Wih,
                                              gru_bih, gru_bhh, Sg, cntg, gxT, E, NEB, epb);

    k_back<<<9, 512, 0, stream>>>(gxT, gru_Whh, gru_bhh, Sg, cntg, relW, relb, gs, flag,
                                  1.f / (float)E, mlp_W1, mlp_b1, ln_g, ln_b, mlp_W2,
                                  mlp_b2, out);
}